// Round 5
// baseline (542.651 us; speedup 1.0000x reference)
//
#include <hip/hip_runtime.h>
#include <hip/hip_bf16.h>

#define N_NODES 100000
#define N_EDGES 1600000
#define NODE_F 128
#define EDGE_F 64
#define OUT_F 32
#define NEG_SLOPE 0.01f
#define E_TILE 256
#define SPAN_CAP 288

// bf16 round-to-nearest-even helpers
__device__ __forceinline__ unsigned short f2bf(float f) {
    unsigned u = __float_as_uint(f);
    unsigned r = u + 0x7fffu + ((u >> 16) & 1u);
    return (unsigned short)(r >> 16);
}
__device__ __forceinline__ float bf2f(unsigned short b) {
    return __uint_as_float((unsigned)b << 16);
}

// ---------- kernel 1: zb = bf16(h @ W_node) ; s_src = z·a_src ; s_dst = z·a_dst ----------
__global__ void k_node_proj(const float* __restrict__ h,
                            const float* __restrict__ W_node,
                            const float* __restrict__ attn_w,
                            unsigned short* __restrict__ zb,
                            float* __restrict__ s_src,
                            float* __restrict__ s_dst) {
    __shared__ float Ws[NODE_F * OUT_F]; // 16 KiB
    for (int i = threadIdx.x; i < NODE_F * OUT_F; i += 256)
        Ws[i] = W_node[i];
    __syncthreads();

    int node = blockIdx.x * 8 + (threadIdx.x >> 5);
    int o = threadIdx.x & 31;
    if (node >= N_NODES) return;

    const float* hrow = h + (size_t)node * NODE_F;
    float acc = 0.f;
#pragma unroll 8
    for (int j = 0; j < NODE_F; ++j)
        acc += hrow[j] * Ws[j * OUT_F + o];

    zb[(size_t)node * OUT_F + o] = f2bf(acc);

    float ps = acc * attn_w[o];
    float pd = acc * attn_w[OUT_F + o];
#pragma unroll
    for (int m = 16; m >= 1; m >>= 1) {
        ps += __shfl_xor(ps, m);
        pd += __shfl_xor(pd, m);
    }
    if (o == 0) {
        s_src[node] = ps;
        s_dst[node] = pd;
    }
}

// ---------- kernel 2: g[e] = edge_feat[e,:]·w_e (w_e computed per block) + dst histogram ----------
__global__ void k_edge_dot(const float* __restrict__ edge_feat,
                           const int* __restrict__ dst,
                           const float* __restrict__ W_edge,
                           const float* __restrict__ attn_w,
                           float* __restrict__ g,
                           int* __restrict__ deg) {
    __shared__ float we_s[EDGE_F];
    if (threadIdx.x < EDGE_F) {
        float a = 0.f;
#pragma unroll
        for (int kk = 0; kk < OUT_F; ++kk)
            a += W_edge[threadIdx.x * OUT_F + kk] * attn_w[2 * OUT_F + kk];
        we_s[threadIdx.x] = a;
    }
    __syncthreads();

    int t = blockIdx.x * 256 + threadIdx.x;
    int e = t >> 2;
    int sub = t & 3;
    if (e >= N_EDGES) return;

    const float4* row = (const float4*)(edge_feat + (size_t)e * EDGE_F);
    float acc = 0.f;
#pragma unroll
    for (int i = 0; i < 4; ++i) {
        int fi = sub + i * 4;
        float4 v = row[fi];
        int b = fi * 4;
        acc += v.x * we_s[b] + v.y * we_s[b + 1] + v.z * we_s[b + 2] + v.w * we_s[b + 3];
    }
    acc += __shfl_xor(acc, 1);
    acc += __shfl_xor(acc, 2);

    if (sub == 0) {
        g[e] = acc;
        atomicAdd(deg + dst[e], 1); // non-returning histogram atomic
    }
}

// ---------- scan kernels: exclusive scan of deg -> offs, cursor ----------
__global__ void k_scan_block(const int* __restrict__ deg,
                             int* __restrict__ offs,
                             int* __restrict__ bsum) {
    __shared__ int wsum[4];
    int i = blockIdx.x * 256 + threadIdx.x;
    int lane = threadIdx.x & 63;
    int wid = threadIdx.x >> 6;
    int v = (i < N_NODES) ? deg[i] : 0;
    int x = v;
#pragma unroll
    for (int d = 1; d < 64; d <<= 1) {
        int y = __shfl_up(x, d);
        if (lane >= d) x += y;
    }
    if (lane == 63) wsum[wid] = x;
    __syncthreads();
    int add = 0;
    for (int w = 0; w < wid; ++w) add += wsum[w];
    int incl = x + add;
    if (i < N_NODES) offs[i] = incl - v;
    if (threadIdx.x == 255) bsum[blockIdx.x] = incl;
}

__global__ void k_scan_bsums(int* __restrict__ bsum, int nb) {
    __shared__ int wsum[8];
    int t = threadIdx.x; // 512
    int lane = t & 63;
    int wid = t >> 6;
    int v = (t < nb) ? bsum[t] : 0;
    int x = v;
#pragma unroll
    for (int d = 1; d < 64; d <<= 1) {
        int y = __shfl_up(x, d);
        if (lane >= d) x += y;
    }
    if (lane == 63) wsum[wid] = x;
    __syncthreads();
    int add = 0;
    for (int w = 0; w < wid; ++w) add += wsum[w];
    int incl = x + add;
    if (t < nb) bsum[t] = incl - v;
}

__global__ void k_scan_add(int* __restrict__ offs,
                           const int* __restrict__ bsum,
                           int* __restrict__ cursor) {
    int i = blockIdx.x * 256 + threadIdx.x;
    if (i < N_NODES) {
        int o = offs[i] + bsum[blockIdx.x];
        offs[i] = o;
        cursor[i] = o;
    }
}

// ---------- kernel 3: logit + exp + packed int4 scatter ----------
__global__ void k_scatter(const int* __restrict__ src,
                          const int* __restrict__ dst,
                          const float* __restrict__ g,
                          const float* __restrict__ s_src,
                          const float* __restrict__ s_dst,
                          int* __restrict__ cursor,
                          int4* __restrict__ perm4) {
    int e = blockIdx.x * 256 + threadIdx.x;
    if (e >= N_EDGES) return;
    int s = src[e], d = dst[e];
    float logit = s_src[s] + s_dst[d] + g[e];
    logit = logit > 0.f ? logit : NEG_SLOPE * logit;
    float ev = __expf(logit); // |logit| small: no overflow, max-shift unnecessary
    int pos = atomicAdd(cursor + d, 1);
    perm4[pos] = make_int4(s, __float_as_int(ev), d, 0);
}

// ---------- kernel 4: edge-parallel segmented aggregation via LDS ----------
// 256 threads = 8 groups x 32 lanes; tile = 256 edges (N_EDGES % 256 == 0)
__global__ __launch_bounds__(256) void k_aggr_seg(
    const int4* __restrict__ perm4,
    const unsigned short* __restrict__ zb,
    const int* __restrict__ offs,
    const int* __restrict__ endp,
    float* __restrict__ gnum,
    float* __restrict__ gden,
    float* __restrict__ out) {
    __shared__ float lds_num[SPAN_CAP * OUT_F];
    __shared__ float lds_den[SPAN_CAP];
    for (int i = threadIdx.x; i < SPAN_CAP * OUT_F; i += 256) lds_num[i] = 0.f;
    for (int i = threadIdx.x; i < SPAN_CAP; i += 256) lds_den[i] = 0.f;
    __syncthreads();

    int e0 = blockIdx.x * E_TILE;
    int n0 = perm4[e0].z; // uniform across block
    int grp = threadIdx.x >> 5;
    int k = threadIdx.x & 31;
    int ebase = e0 + grp * 32;

#pragma unroll 2
    for (int j = 0; j < 32; j += 4) {
        int4 pa = perm4[ebase + j + 0];
        int4 pb = perm4[ebase + j + 1];
        int4 pc = perm4[ebase + j + 2];
        int4 pd = perm4[ebase + j + 3];
        float za = bf2f(zb[(size_t)pa.x * OUT_F + k]);
        float zv = bf2f(zb[(size_t)pb.x * OUT_F + k]);
        float zc = bf2f(zb[(size_t)pc.x * OUT_F + k]);
        float zd = bf2f(zb[(size_t)pd.x * OUT_F + k]);
        float ea = __int_as_float(pa.y);
        float eb = __int_as_float(pb.y);
        float ec = __int_as_float(pc.y);
        float ed = __int_as_float(pd.y);
        int la = pa.z - n0, lb = pb.z - n0, lc = pc.z - n0, ld = pd.z - n0;

        if (la < SPAN_CAP) { atomicAdd(&lds_num[la * OUT_F + k], ea * za); if (k == 0) atomicAdd(&lds_den[la], ea); }
        else { atomicAdd(&gnum[(size_t)pa.z * OUT_F + k], ea * za); if (k == 0) atomicAdd(&gden[pa.z], ea); }
        if (lb < SPAN_CAP) { atomicAdd(&lds_num[lb * OUT_F + k], eb * zv); if (k == 0) atomicAdd(&lds_den[lb], eb); }
        else { atomicAdd(&gnum[(size_t)pb.z * OUT_F + k], eb * zv); if (k == 0) atomicAdd(&gden[pb.z], eb); }
        if (lc < SPAN_CAP) { atomicAdd(&lds_num[lc * OUT_F + k], ec * zc); if (k == 0) atomicAdd(&lds_den[lc], ec); }
        else { atomicAdd(&gnum[(size_t)pc.z * OUT_F + k], ec * zc); if (k == 0) atomicAdd(&gden[pc.z], ec); }
        if (ld < SPAN_CAP) { atomicAdd(&lds_num[ld * OUT_F + k], ed * zd); if (k == 0) atomicAdd(&lds_den[ld], ed); }
        else { atomicAdd(&gnum[(size_t)pd.z * OUT_F + k], ed * zd); if (k == 0) atomicAdd(&gden[pd.z], ed); }
    }
    __syncthreads();

    int n_last = perm4[e0 + E_TILE - 1].z; // uniform
    for (int nid = n0 + grp; nid <= n_last; nid += 8) {
        int li = nid - n0;
        if (li >= SPAN_CAP) break; // overflow nodes handled via global atomics + finalize
        float den = lds_den[li];
        if (den == 0.f) continue; // zero-degree gap
        float nm = lds_num[li * OUT_F + k];
        int st = offs[nid], en = endp[nid];
        if (st >= e0 && en <= e0 + E_TILE) {
            out[(size_t)nid * OUT_F + k] = nm / fmaxf(den, 1e-20f); // interior: direct
        } else {
            atomicAdd(&gnum[(size_t)nid * OUT_F + k], nm); // boundary: partial sums
            if (k == 0) atomicAdd(&gden[nid], den);
        }
    }
}

// ---------- kernel 5: finalize boundary / overflow / empty nodes ----------
__global__ void k_finalize(const int* __restrict__ offs,
                           const int* __restrict__ endp,
                           const int4* __restrict__ perm4,
                           const float* __restrict__ gnum,
                           const float* __restrict__ gden,
                           float* __restrict__ out) {
    int node = blockIdx.x * 8 + (threadIdx.x >> 5);
    int k = threadIdx.x & 31;
    if (node >= N_NODES) return;
    int st = offs[node], en = endp[node];
    if (st == en) {
        out[(size_t)node * OUT_F + k] = 0.f;
        return;
    }
    int t0 = st >> 8, t1 = (en - 1) >> 8;
    bool needs = (t0 != t1);
    if (!needs) {
        int nf = perm4[t0 << 8].z; // first node of that tile
        needs = (node - nf) >= SPAN_CAP;
    }
    if (needs)
        out[(size_t)node * OUT_F + k] =
            gnum[(size_t)node * OUT_F + k] / fmaxf(gden[node], 1e-20f);
}

extern "C" void kernel_launch(void* const* d_in, const int* in_sizes, int n_in,
                              void* d_out, int out_size, void* d_ws, size_t ws_size,
                              hipStream_t stream) {
    const float* h         = (const float*)d_in[0];
    const float* edge_feat = (const float*)d_in[1];
    const int*   src       = (const int*)d_in[2];
    const int*   dst       = (const int*)d_in[3];
    const float* W_node    = (const float*)d_in[4];
    const float* W_edge    = (const float*)d_in[5];
    const float* attn_w    = (const float*)d_in[6];
    float* out = (float*)d_out;

    char* ws = (char*)d_ws;
    size_t off = 0;
    auto alloc = [&](size_t bytes) {
        void* p = ws + off;
        off += (bytes + 255) & ~(size_t)255;
        return p;
    };
    unsigned short* zb = (unsigned short*)alloc((size_t)N_NODES * OUT_F * sizeof(unsigned short));
    float* s_src  = (float*)alloc((size_t)N_NODES * sizeof(float));
    float* s_dst  = (float*)alloc((size_t)N_NODES * sizeof(float));
    float* g      = (float*)alloc((size_t)N_EDGES * sizeof(float));
    int*   offs   = (int*)alloc((size_t)N_NODES * sizeof(int));
    int*   cursor = (int*)alloc((size_t)N_NODES * sizeof(int));
    int*   bsum   = (int*)alloc(1024 * sizeof(int));
    int4*  perm4  = (int4*)alloc((size_t)N_EDGES * sizeof(int4));
    // contiguous zero region: deg, gden, gnum
    char*  zero_base = ws + off;
    int*   deg    = (int*)alloc((size_t)N_NODES * sizeof(int));
    float* gden   = (float*)alloc((size_t)N_NODES * sizeof(float));
    float* gnum   = (float*)alloc((size_t)N_NODES * OUT_F * sizeof(float));
    size_t zero_bytes = (ws + off) - zero_base;

    const int NB = (N_NODES + 255) / 256; // 391 scan blocks

    hipMemsetAsync(zero_base, 0, zero_bytes, stream);

    k_node_proj<<<(N_NODES + 7) / 8, 256, 0, stream>>>(h, W_node, attn_w, zb, s_src, s_dst);

    {
        int total = N_EDGES * 4;
        k_edge_dot<<<(total + 255) / 256, 256, 0, stream>>>(edge_feat, dst, W_edge, attn_w, g, deg);
    }
    k_scan_block<<<NB, 256, 0, stream>>>(deg, offs, bsum);
    k_scan_bsums<<<1, 512, 0, stream>>>(bsum, NB);
    k_scan_add<<<NB, 256, 0, stream>>>(offs, bsum, cursor);

    k_scatter<<<(N_EDGES + 255) / 256, 256, 0, stream>>>(
        src, dst, g, s_src, s_dst, cursor, perm4);

    k_aggr_seg<<<N_EDGES / E_TILE, 256, 0, stream>>>(
        perm4, zb, offs, cursor, gnum, gden, out);

    k_finalize<<<(N_NODES + 7) / 8, 256, 0, stream>>>(
        offs, cursor, perm4, gnum, gden, out);
}

// Round 6
// 329.594 us; speedup vs baseline: 1.6464x; 1.6464x over previous
//
#include <hip/hip_runtime.h>
#include <hip/hip_bf16.h>

#define N_NODES 100000
#define N_EDGES 1600000
#define NODE_F 128
#define EDGE_F 64
#define OUT_F 32
#define NEG_SLOPE 0.01f

// bf16 round-to-nearest-even helpers
__device__ __forceinline__ unsigned short f2bf(float f) {
    unsigned u = __float_as_uint(f);
    unsigned r = u + 0x7fffu + ((u >> 16) & 1u);
    return (unsigned short)(r >> 16);
}
__device__ __forceinline__ float bf2f(unsigned short b) {
    return __uint_as_float((unsigned)b << 16);
}

// ---------- kernel 1: zb = bf16(h @ W_node) ; s_src = z·a_src ; s_dst = z·a_dst ----------
__global__ void k_node_proj(const float* __restrict__ h,
                            const float* __restrict__ W_node,
                            const float* __restrict__ attn_w,
                            unsigned short* __restrict__ zb,
                            float* __restrict__ s_src,
                            float* __restrict__ s_dst) {
    __shared__ float Ws[NODE_F * OUT_F]; // 16 KiB
    for (int i = threadIdx.x; i < NODE_F * OUT_F; i += 256)
        Ws[i] = W_node[i];
    __syncthreads();

    int node = blockIdx.x * 8 + (threadIdx.x >> 5);
    int o = threadIdx.x & 31;
    if (node >= N_NODES) return;

    const float* hrow = h + (size_t)node * NODE_F;
    float acc = 0.f;
#pragma unroll 8
    for (int j = 0; j < NODE_F; ++j)
        acc += hrow[j] * Ws[j * OUT_F + o];

    zb[(size_t)node * OUT_F + o] = f2bf(acc);

    float ps = acc * attn_w[o];
    float pd = acc * attn_w[OUT_F + o];
#pragma unroll
    for (int m = 16; m >= 1; m >>= 1) {
        ps += __shfl_xor(ps, m);
        pd += __shfl_xor(pd, m);
    }
    if (o == 0) {
        s_src[node] = ps;
        s_dst[node] = pd;
    }
}

// ---------- kernel 2: g[e] = edge_feat[e,:]·w_e (w_e computed per block) + dst histogram ----------
__global__ void k_edge_dot(const float* __restrict__ edge_feat,
                           const int* __restrict__ dst,
                           const float* __restrict__ W_edge,
                           const float* __restrict__ attn_w,
                           float* __restrict__ g,
                           int* __restrict__ deg) {
    __shared__ float we_s[EDGE_F];
    if (threadIdx.x < EDGE_F) {
        float a = 0.f;
#pragma unroll
        for (int kk = 0; kk < OUT_F; ++kk)
            a += W_edge[threadIdx.x * OUT_F + kk] * attn_w[2 * OUT_F + kk];
        we_s[threadIdx.x] = a;
    }
    __syncthreads();

    int t = blockIdx.x * 256 + threadIdx.x;
    int e = t >> 2;
    int sub = t & 3;
    if (e >= N_EDGES) return;

    const float4* row = (const float4*)(edge_feat + (size_t)e * EDGE_F);
    float acc = 0.f;
#pragma unroll
    for (int i = 0; i < 4; ++i) {
        int fi = sub + i * 4;
        float4 v = row[fi];
        int b = fi * 4;
        acc += v.x * we_s[b] + v.y * we_s[b + 1] + v.z * we_s[b + 2] + v.w * we_s[b + 3];
    }
    acc += __shfl_xor(acc, 1);
    acc += __shfl_xor(acc, 2);

    if (sub == 0) {
        g[e] = acc;
        atomicAdd(deg + dst[e], 1); // non-returning histogram atomic
    }
}

// ---------- scan kernels: exclusive scan of deg -> offs, cursor ----------
__global__ void k_scan_block(const int* __restrict__ deg,
                             int* __restrict__ offs,
                             int* __restrict__ bsum) {
    __shared__ int wsum[4];
    int i = blockIdx.x * 256 + threadIdx.x;
    int lane = threadIdx.x & 63;
    int wid = threadIdx.x >> 6;
    int v = (i < N_NODES) ? deg[i] : 0;
    int x = v;
#pragma unroll
    for (int d = 1; d < 64; d <<= 1) {
        int y = __shfl_up(x, d);
        if (lane >= d) x += y;
    }
    if (lane == 63) wsum[wid] = x;
    __syncthreads();
    int add = 0;
    for (int w = 0; w < wid; ++w) add += wsum[w];
    int incl = x + add;
    if (i < N_NODES) offs[i] = incl - v;
    if (threadIdx.x == 255) bsum[blockIdx.x] = incl;
}

__global__ void k_scan_bsums(int* __restrict__ bsum, int nb) {
    __shared__ int wsum[8];
    int t = threadIdx.x; // 512
    int lane = t & 63;
    int wid = t >> 6;
    int v = (t < nb) ? bsum[t] : 0;
    int x = v;
#pragma unroll
    for (int d = 1; d < 64; d <<= 1) {
        int y = __shfl_up(x, d);
        if (lane >= d) x += y;
    }
    if (lane == 63) wsum[wid] = x;
    __syncthreads();
    int add = 0;
    for (int w = 0; w < wid; ++w) add += wsum[w];
    int incl = x + add;
    if (t < nb) bsum[t] = incl - v;
}

__global__ void k_scan_add(int* __restrict__ offs,
                           const int* __restrict__ bsum,
                           int* __restrict__ cursor) {
    int i = blockIdx.x * 256 + threadIdx.x;
    if (i < N_NODES) {
        int o = offs[i] + bsum[blockIdx.x];
        offs[i] = o;
        cursor[i] = o;
    }
}

// ---------- kernel 3: logit + exp + packed int4 scatter ----------
__global__ void k_scatter(const int* __restrict__ src,
                          const int* __restrict__ dst,
                          const float* __restrict__ g,
                          const float* __restrict__ s_src,
                          const float* __restrict__ s_dst,
                          int* __restrict__ cursor,
                          int4* __restrict__ perm4) {
    int e = blockIdx.x * 256 + threadIdx.x;
    if (e >= N_EDGES) return;
    int s = src[e], d = dst[e];
    float logit = s_src[s] + s_dst[d] + g[e];
    logit = logit > 0.f ? logit : NEG_SLOPE * logit;
    float ev = __expf(logit); // |logit| small: no overflow, max-shift unnecessary
    int pos = atomicAdd(cursor + d, 1);
    perm4[pos] = make_int4(s, __float_as_int(ev), d, 0);
}

// ---------- kernel 4: position-parallel segmented aggregation ----------
// 32-lane group per aligned 32-edge chunk; lanes = 32 output channels.
// Interior buckets ((st>>5)==((en-1)>>5)) stored directly; crossing buckets
// accumulate via global atomics and are divided in k_finalize.
__global__ __launch_bounds__(256) void k_aggr_pos(
    const int4* __restrict__ perm4,
    const unsigned short* __restrict__ zb,
    const int* __restrict__ offs,
    const int* __restrict__ endp,
    float* __restrict__ gnum,
    float* __restrict__ gden,
    float* __restrict__ out) {
    int grp = blockIdx.x * 8 + (threadIdx.x >> 5);
    int k = threadIdx.x & 31;
    int ebase = grp * 32; // N_EDGES % 32 == 0

    float acc = 0.f, den = 0.f;
    int cur = perm4[ebase].z; // wave-uniform within group

#pragma unroll
    for (int j = 0; j < 32; ++j) {
        int4 pj = perm4[ebase + j]; // uniform across group -> cache broadcast
        if (pj.z != cur) {
            // mid-chunk flush: cur's bucket ended inside this chunk.
            // interior iff it also STARTED here (st >= ebase).
            int st = offs[cur];
            if (st >= ebase) {
                out[(size_t)cur * OUT_F + k] = acc / fmaxf(den, 1e-20f);
            } else {
                atomicAdd(&gnum[(size_t)cur * OUT_F + k], acc);
                if (k == 0) atomicAdd(&gden[cur], den);
            }
            acc = 0.f;
            den = 0.f;
            cur = pj.z;
        }
        float evj = __int_as_float(pj.y);
        acc += evj * bf2f(zb[(size_t)pj.x * OUT_F + k]);
        den += evj; // same value in every lane -> no reduction needed
    }
    // final flush
    {
        int st = offs[cur], en = endp[cur];
        if (st >= ebase && en <= ebase + 32) {
            out[(size_t)cur * OUT_F + k] = acc / fmaxf(den, 1e-20f);
        } else {
            atomicAdd(&gnum[(size_t)cur * OUT_F + k], acc);
            if (k == 0) atomicAdd(&gden[cur], den);
        }
    }
}

// ---------- kernel 5: finalize chunk-crossing / empty nodes ----------
__global__ void k_finalize(const int* __restrict__ offs,
                           const int* __restrict__ endp,
                           const float* __restrict__ gnum,
                           const float* __restrict__ gden,
                           float* __restrict__ out) {
    int node = blockIdx.x * 8 + (threadIdx.x >> 5);
    int k = threadIdx.x & 31;
    if (node >= N_NODES) return;
    int st = offs[node], en = endp[node];
    if (st == en) {
        out[(size_t)node * OUT_F + k] = 0.f;
        return;
    }
    if ((st >> 5) != ((en - 1) >> 5)) // bucket crossed a 32-edge chunk boundary
        out[(size_t)node * OUT_F + k] =
            gnum[(size_t)node * OUT_F + k] / fmaxf(gden[node], 1e-20f);
}

extern "C" void kernel_launch(void* const* d_in, const int* in_sizes, int n_in,
                              void* d_out, int out_size, void* d_ws, size_t ws_size,
                              hipStream_t stream) {
    const float* h         = (const float*)d_in[0];
    const float* edge_feat = (const float*)d_in[1];
    const int*   src       = (const int*)d_in[2];
    const int*   dst       = (const int*)d_in[3];
    const float* W_node    = (const float*)d_in[4];
    const float* W_edge    = (const float*)d_in[5];
    const float* attn_w    = (const float*)d_in[6];
    float* out = (float*)d_out;

    char* ws = (char*)d_ws;
    size_t off = 0;
    auto alloc = [&](size_t bytes) {
        void* p = ws + off;
        off += (bytes + 255) & ~(size_t)255;
        return p;
    };
    unsigned short* zb = (unsigned short*)alloc((size_t)N_NODES * OUT_F * sizeof(unsigned short));
    float* s_src  = (float*)alloc((size_t)N_NODES * sizeof(float));
    float* s_dst  = (float*)alloc((size_t)N_NODES * sizeof(float));
    float* g      = (float*)alloc((size_t)N_EDGES * sizeof(float));
    int*   offs   = (int*)alloc((size_t)N_NODES * sizeof(int));
    int*   cursor = (int*)alloc((size_t)N_NODES * sizeof(int));
    int*   bsum   = (int*)alloc(1024 * sizeof(int));
    int4*  perm4  = (int4*)alloc((size_t)N_EDGES * sizeof(int4));
    // contiguous zero region: deg, gden, gnum
    char*  zero_base = ws + off;
    int*   deg    = (int*)alloc((size_t)N_NODES * sizeof(int));
    float* gden   = (float*)alloc((size_t)N_NODES * sizeof(float));
    float* gnum   = (float*)alloc((size_t)N_NODES * OUT_F * sizeof(float));
    size_t zero_bytes = (ws + off) - zero_base;

    const int NB = (N_NODES + 255) / 256; // 391 scan blocks

    hipMemsetAsync(zero_base, 0, zero_bytes, stream);

    k_node_proj<<<(N_NODES + 7) / 8, 256, 0, stream>>>(h, W_node, attn_w, zb, s_src, s_dst);

    {
        int total = N_EDGES * 4;
        k_edge_dot<<<(total + 255) / 256, 256, 0, stream>>>(edge_feat, dst, W_edge, attn_w, g, deg);
    }
    k_scan_block<<<NB, 256, 0, stream>>>(deg, offs, bsum);
    k_scan_bsums<<<1, 512, 0, stream>>>(bsum, NB);
    k_scan_add<<<NB, 256, 0, stream>>>(offs, bsum, cursor);

    k_scatter<<<(N_EDGES + 255) / 256, 256, 0, stream>>>(
        src, dst, g, s_src, s_dst, cursor, perm4);

    k_aggr_pos<<<N_EDGES / 32 / 8, 256, 0, stream>>>(
        perm4, zb, offs, cursor, gnum, gden, out);

    k_finalize<<<(N_NODES + 7) / 8, 256, 0, stream>>>(
        offs, cursor, gnum, gden, out);
}